// Round 10
// baseline (130.165 us; speedup 1.0000x reference)
//
#include <hip/hip_runtime.h>
#include <stdint.h>

// 2-layer GCN + global mean pool + MLP head. N=100000, E=1600000, G=512. fp32.
//
// Fully scalarized: the whole GNN reduces to 3 scalar segment-sums per node
// (deg; tf = sum xd[src]; (T,D,A) = sum (u,v,|u|)[src]) + a rank-3 epilogue:
//   h2[d,j] = relu(a*alpha_j + b*beta_j + c*gamma_j + b2_j), alpha/beta/gamma
//   fold W1/b1 through W2 (exact for any b1). Then mean-pool + MLP head.
//
// Round-28 theme: delete the memset dispatch and ALL global atomics via
// STATIC per-(bucket,chunk) slotting. ebuf cell (b,c) = 64 ints at
// b*cap2 + c*64 (mean fill 21, sigma 4.6 -> 9-sigma headroom; inputs are
// deterministic). sortscatter: no gcur atomic, no reservation stall; writes
// a counts matrix cnts[b][c] plainly. nsort: reads its counts row, scans,
// ragged-copies cells into LDS (cells are <=256B, coalesced), then the
// verified r26 one-pass register-rank scheme; node-sorted array is built
// IN THE SAME LDS buffer (edges+ranks persist in registers) and flushed
// coalesced to dense ebuf2. k_t / k_tda_pool byte-identical to r27.
// Dispatches: 5 -> 4 (memset gone).
// Ledger: dur = 41 us harness poison-fill (fixed) + ~87 us pipeline.
// Banned forever: per-edge global atomics (r10/r13); agent-scope spin
// grid-barriers (r21); cooperative-launch API (r19). Known-bad: split
// LDS-bin back-end (r20); wave-private cursors (r23 neutral).

#define CHUNK   8192
#define MAXBUCK 400     // NBUCK = ceil(100000/256) = 391
#define BSH     8
#define BN      256
#define SLOT    64      // ints per (bucket,chunk) cell; mean 21, 9-sigma safe
#define CROW    200     // padded counts-row stride (nch = 196)
#define CAP     8192    // dense ebuf2 slots per bucket (max ~4400 + pad)
#define ECAP3   8960    // nsort LDS stage: padded total <= ecnt + 3*256

static inline size_t align_up(size_t x, size_t a){ return (x + a - 1) & ~(a - 1); }

// --- hist(+rank) + scan + sorted LDS build + static-slot coalesced flush ---
__global__ void __launch_bounds__(1024) k_sortscatter(
        const int* __restrict__ src, const int* __restrict__ dst,
        int* __restrict__ cnts, int* __restrict__ ebuf,
        int E, int nbuck, int cap2){
    __shared__ int    h[MAXBUCK];       // hist -> local sorted start
    __shared__ int    gofull[MAXBUCK];  // b*cap2 + c*SLOT - localstart[b]
    __shared__ int    lds_e[CHUNK];     // sorted packed edges
    __shared__ unsigned short lds_b[CHUNK]; // bucket id per sorted slot
    __shared__ int    wsum[16];
    int t = threadIdx.x;
    int c = blockIdx.x;
    if (t < MAXBUCK) h[t] = 0;
    __syncthreads();
    int base = c * CHUNK;
    int end = min(base + CHUNK, E);
    int ntot = end - base;
    int i = base + t * 8;
    bool vec = (i + 7 < end);
    int4 sa0, sa1, da0, da1;
    int r0=0,r1=0,r2=0,r3=0,r4=0,r5=0,r6=0,r7=0;
    if (vec){
        sa0 = *(const int4*)(src + i);
        sa1 = *(const int4*)(src + i + 4);
        da0 = *(const int4*)(dst + i);
        da1 = *(const int4*)(dst + i + 4);
        r0 = atomicAdd(&h[da0.x >> BSH], 1);   // rank captured in hist pass
        r1 = atomicAdd(&h[da0.y >> BSH], 1);
        r2 = atomicAdd(&h[da0.z >> BSH], 1);
        r3 = atomicAdd(&h[da0.w >> BSH], 1);
        r4 = atomicAdd(&h[da1.x >> BSH], 1);
        r5 = atomicAdd(&h[da1.y >> BSH], 1);
        r6 = atomicAdd(&h[da1.z >> BSH], 1);
        r7 = atomicAdd(&h[da1.w >> BSH], 1);
    }
    int vend = base + (ntot & ~7);
    int srem = 0, drem = 0, rrem = 0;
    bool hasrem = false;
    for (int j = vend + t; j < end; j += 1024){   // <=7 edges total
        srem = src[j]; drem = dst[j];
        rrem = atomicAdd(&h[drem >> BSH], 1);
        hasrem = true;
    }
    __syncthreads();
    // exclusive scan over h[0..nbuck); no global reservation needed
    int v = (t < nbuck) ? h[t] : 0;
    int lane = t & 63, wv = t >> 6;
    int sc = v;
    #pragma unroll
    for (int off = 1; off < 64; off <<= 1){
        int o = __shfl_up(sc, off);
        if (lane >= off) sc += o;
    }
    if (lane == 63) wsum[wv] = sc;
    __syncthreads();
    if (t < nbuck){
        int wo = 0;
        #pragma unroll
        for (int k = 0; k < 16; ++k) if (k < wv) wo += wsum[k];
        int excl = sc - v + wo;          // local sorted start of bucket t
        h[t] = excl;
        gofull[t] = t * cap2 + c * SLOT - excl;   // STATIC slot base
        cnts[t * CROW + c] = v;                   // plain store, no atomic
    }
    __syncthreads();
    // sorted LDS build from register-held ranks (no second atomic pass)
    if (vec){
        int b0 = da0.x >> BSH, b1 = da0.y >> BSH, b2 = da0.z >> BSH, b3 = da0.w >> BSH;
        int b4 = da1.x >> BSH, b5 = da1.y >> BSH, b6 = da1.z >> BSH, b7 = da1.w >> BSH;
        int p0 = h[b0] + r0, p1 = h[b1] + r1, p2 = h[b2] + r2, p3 = h[b3] + r3;
        int p4 = h[b4] + r4, p5 = h[b5] + r5, p6 = h[b6] + r6, p7 = h[b7] + r7;
        lds_e[p0] = (sa0.x << BSH) | (da0.x & (BN - 1));  lds_b[p0] = (unsigned short)b0;
        lds_e[p1] = (sa0.y << BSH) | (da0.y & (BN - 1));  lds_b[p1] = (unsigned short)b1;
        lds_e[p2] = (sa0.z << BSH) | (da0.z & (BN - 1));  lds_b[p2] = (unsigned short)b2;
        lds_e[p3] = (sa0.w << BSH) | (da0.w & (BN - 1));  lds_b[p3] = (unsigned short)b3;
        lds_e[p4] = (sa1.x << BSH) | (da1.x & (BN - 1));  lds_b[p4] = (unsigned short)b4;
        lds_e[p5] = (sa1.y << BSH) | (da1.y & (BN - 1));  lds_b[p5] = (unsigned short)b5;
        lds_e[p6] = (sa1.z << BSH) | (da1.z & (BN - 1));  lds_b[p6] = (unsigned short)b6;
        lds_e[p7] = (sa1.w << BSH) | (da1.w & (BN - 1));  lds_b[p7] = (unsigned short)b7;
    }
    if (hasrem){
        int b = drem >> BSH;
        int p = h[b] + rrem;
        lds_e[p] = (srem << BSH) | (drem & (BN - 1));
        lds_b[p] = (unsigned short)b;
    }
    __syncthreads();
    // coalesced flush: consecutive lanes -> consecutive sorted slots
    for (int j = t; j < ntot; j += 1024){
        int b = lds_b[j];
        ebuf[gofull[b] + j] = lds_e[j];
    }
}

// --- node-level sort within bucket: counts-row scan + ragged cell copy into
//     LDS, one-pass register rank capture, in-place sorted build, coalesced
//     flush. degree/dinv/xd fall out free. Segments padded to %4. ---
__global__ void __launch_bounds__(512) k_nsort(
        const int* __restrict__ ebuf, const int* __restrict__ cnts,
        const float* __restrict__ x, float* __restrict__ dinv,
        float* __restrict__ xd, int2* __restrict__ noffs2,
        int* __restrict__ ebuf2, int N, int nch, int cap2){
    __shared__ int stage[ECAP3];        // staged edges, then sorted result
    __shared__ int ccc[BN];             // cell counts (nch <= 256)
    __shared__ int cro[BN];             // cell exclusive offsets
    __shared__ int cnt[BN];
    __shared__ int wsum[4];
    __shared__ int secnt, sptot;
    int b = blockIdx.x, node0 = b << BSH, t = threadIdx.x;
    int lane = t & 63, wv = t >> 6;
    // cell counts row + scan (exclusive) over 256 entries
    int vcell = 0;
    if (t < BN){
        vcell = (t < nch) ? cnts[b * CROW + t] : 0;
        int scc = vcell;
        #pragma unroll
        for (int off = 1; off < 64; off <<= 1){
            int o = __shfl_up(scc, off);
            if (lane >= off) scc += o;
        }
        if (lane == 63) wsum[wv] = scc;
        ccc[t] = vcell;
        cro[t] = scc - vcell;            // intra-wave exclusive
        cnt[t] = 0;
    }
    __syncthreads();
    if (t < BN){
        int wo = 0;
        #pragma unroll
        for (int k = 0; k < 4; ++k) if (k < wv) wo += wsum[k];
        cro[t] += wo;
    }
    if (t == 0) secnt = wsum[0] + wsum[1] + wsum[2] + wsum[3];
    __syncthreads();
    int ecnt = secnt;
    // ragged copy: wave w handles cells w, w+8, ... (cell <= 64 entries)
    {
        int w8 = t >> 6;
        for (int c = w8; c < nch; c += 8){
            int k = ccc[c];
            if (lane < k)
                stage[cro[c] + lane] = ebuf[(size_t)b * cap2 + c * SLOT + lane];
        }
    }
    __syncthreads();
    // one-pass hist + rank capture from staged edges (registers persist)
    int e4 = ecnt & ~3;
    int4 qv[4], rv[4];
    #pragma unroll
    for (int k = 0; k < 4; ++k){
        int i = t * 4 + k * 2048;
        if (i < e4){
            qv[k] = *(const int4*)(stage + i);
            rv[k].x = atomicAdd(&cnt[qv[k].x & (BN - 1)], 1);
            rv[k].y = atomicAdd(&cnt[qv[k].y & (BN - 1)], 1);
            rv[k].z = atomicAdd(&cnt[qv[k].z & (BN - 1)], 1);
            rv[k].w = atomicAdd(&cnt[qv[k].w & (BN - 1)], 1);
        }
    }
    int erem = 0, rrem = 0;
    bool hasrem = false;
    for (int j = e4 + t; j < ecnt; j += 512){     // <=3 edges total
        erem = stage[j];
        rrem = atomicAdd(&cnt[erem & (BN - 1)], 1);
        hasrem = true;
    }
    __syncthreads();
    int myc = 0, v = 0, sc = 0;
    if (t < BN){
        myc = cnt[t];
        v = (myc + 3) & ~3;               // padded count -> aligned starts
        sc = v;
        #pragma unroll
        for (int off = 1; off < 64; off <<= 1){
            int o = __shfl_up(sc, off);   // waves 0..3 fully active
            if (lane >= off) sc += o;
        }
        if (lane == 63) wsum[wv] = sc;
    }
    __syncthreads();
    if (t < BN){
        int wo = 0;
        #pragma unroll
        for (int k = 0; k < 4; ++k) if (k < wv) wo += wsum[k];
        int excl = sc - v + wo;           // exclusive padded prefix (local)
        cnt[t] = excl;
        int n = node0 + t;
        if (n < N){
            noffs2[n] = make_int2(b * CAP + excl, myc);
            float di = rsqrtf((float)myc + 1.0f);
            dinv[n] = di;
            xd[n] = x[n] * di;
        }
    }
    if (t == 0) sptot = wsum[0] + wsum[1] + wsum[2] + wsum[3];
    __syncthreads();
    // in-place sorted build (stage reads all done; values in registers)
    #pragma unroll
    for (int k = 0; k < 4; ++k){
        int i = t * 4 + k * 2048;
        if (i < e4){
            stage[cnt[qv[k].x & (BN - 1)] + rv[k].x] = qv[k].x >> BSH;
            stage[cnt[qv[k].y & (BN - 1)] + rv[k].y] = qv[k].y >> BSH;
            stage[cnt[qv[k].z & (BN - 1)] + rv[k].z] = qv[k].z >> BSH;
            stage[cnt[qv[k].w & (BN - 1)] + rv[k].w] = qv[k].w >> BSH;
        }
    }
    if (hasrem)
        stage[cnt[erem & (BN - 1)] + rrem] = erem >> BSH;
    __syncthreads();
    // coalesced flush (pad slots carry garbage; never read downstream)
    int ptot = sptot;
    for (int j = t; j < ptot; j += 512)
        ebuf2[b * CAP + j] = stage[j];
}

// --- tf[n] = sum xd[src]; 4 threads per node, shfl combine.
//     Also emits gstart[0..G] from batch transitions. ---
__global__ void __launch_bounds__(512) k_t(
        const int* __restrict__ ebuf2, const int2* __restrict__ noffs2,
        const float* __restrict__ xd, const float* __restrict__ dinv,
        const int* __restrict__ batch, int* __restrict__ gstart,
        float2* __restrict__ uv, int N, int G){
    int idx = blockIdx.x * 512 + threadIdx.x;
    int n = idx >> 2, q = idx & 3;
    float s = 0.f;
    int2 o = make_int2(0, 0);
    if (n < N){
        o = noffs2[n];
        int vEnd = o.x + (o.y & ~3);
        for (int i = o.x + q * 4; i < vEnd; i += 16){
            int4 e = *(const int4*)(ebuf2 + i);
            s += xd[e.x] + xd[e.y] + xd[e.z] + xd[e.w];
        }
        if (q == 0)
            for (int i = vEnd; i < o.x + o.y; ++i) s += xd[ebuf2[i]];
    }
    s += __shfl_xor(s, 1);
    s += __shfl_xor(s, 2);
    if (n < N && q == 0){
        float di = dinv[n];
        uv[n] = make_float2(di * di * (s + xd[n]), di);
        // graph boundary emission: every g in [0,G] written exactly once
        int b0 = batch[n];
        int bp = (n == 0) ? -1 : batch[n - 1];
        for (int g = bp + 1; g <= b0; ++g) gstart[g] = n;
        if (n == N - 1)
            for (int g = b0 + 1; g <= G; ++g) gstart[g] = N;
    }
}

// --- fused: per-node (T,D,A) (pair-per-node) + abg fold + pool + head ---
__global__ void __launch_bounds__(512) k_tda_pool(
        const int* __restrict__ ebuf2, const int2* __restrict__ noffs2,
        const float2* __restrict__ uv, const int* __restrict__ gstart,
        const float* __restrict__ W1, const float* __restrict__ b1,
        const float* __restrict__ W2, const float* __restrict__ b2,
        const float* __restrict__ Wl1, const float* __restrict__ bl1,
        const float* __restrict__ Wl2, const float* __restrict__ bl2,
        float* __restrict__ out, int N){
    __shared__ float sa[256], sb[256], sc[256];
    __shared__ float psum[512];
    __shared__ float pooled[128];
    __shared__ float h3s[64];
    int g = blockIdx.x;
    int t = threadIdx.x;           // 512
    int col = t & 127, sub = t >> 7;   // 4 subs of 128 cols
    float al = 0.f, be = 0.f, ga = 0.f;
    #pragma unroll
    for (int c = 0; c < 64; ++c){
        float w2 = W2[c * 128 + col];
        al = fmaf(W1[c], w2, al);
        be = fmaf(b1[c], w2, be);
        ga = fmaf(fabsf(W1[c]), w2, ga);
    }
    float b2j = b2[col];
    int lo = gstart[g], lo2 = gstart[g + 1];
    int cnt = lo2 - lo;
    float pool = 0.f;
    int k = t >> 1, half = t & 1;
    for (int base = lo; base < lo2; base += 256){
        int nn = min(256, lo2 - base);
        float T = 0.f, D = 0.f, A = 0.f;
        if (k < nn){
            int n = base + k;
            int2 o = noffs2[n];
            int vEnd = o.x + (o.y & ~3);
            for (int i = o.x + half * 4; i < vEnd; i += 8){
                int4 q = *(const int4*)(ebuf2 + i);
                float2 w0 = uv[q.x], w1 = uv[q.y], w2v = uv[q.z], w3 = uv[q.w];
                T += w0.x + w1.x + w2v.x + w3.x;
                D += w0.y + w1.y + w2v.y + w3.y;
                A += fabsf(w0.x) + fabsf(w1.x) + fabsf(w2v.x) + fabsf(w3.x);
            }
            if (half == 0)
                for (int i = vEnd; i < o.x + o.y; ++i){
                    float2 wv = uv[ebuf2[i]];
                    T += wv.x; D += wv.y; A += fabsf(wv.x);
                }
        }
        T += __shfl_xor(T, 1);
        D += __shfl_xor(D, 1);
        A += __shfl_xor(A, 1);
        if (k < nn && half == 0){
            float2 wv = uv[base + k];
            float hv = 0.5f * wv.y;
            sa[k] = hv * (T + wv.x);
            sb[k] = hv * (D + wv.y);
            sc[k] = hv * (A + fabsf(wv.x));
        }
        __syncthreads();
        for (int u = sub; u < nn; u += 4){
            float h = fmaf(sa[u], al, fmaf(sb[u], be, fmaf(sc[u], ga, b2j)));
            pool += fmaxf(h, 0.f);
        }
        __syncthreads();
    }
    psum[t] = pool;
    __syncthreads();
    if (t < 128)
        pooled[t] = (psum[t] + psum[t + 128] + psum[t + 256] + psum[t + 384])
                    / (float)(cnt > 0 ? cnt : 1);
    __syncthreads();
    if (t < 64){
        float a = bl1[t];
        #pragma unroll
        for (int kk = 0; kk < 128; ++kk) a = fmaf(pooled[kk], Wl1[kk * 64 + t], a);
        h3s[t] = fmaxf(a, 0.f);
    }
    __syncthreads();
    if (t < 4){
        float o = bl2[t];
        #pragma unroll
        for (int j = 0; j < 64; ++j) o = fmaf(h3s[j], Wl2[j * 4 + t], o);
        out[g * 4 + t] = o;
    }
}

extern "C" void kernel_launch(void* const* d_in, const int* in_sizes, int n_in,
                              void* d_out, int out_size, void* d_ws, size_t ws_size,
                              hipStream_t stream) {
    const float* x    = (const float*)d_in[0];
    const int*   ei   = (const int*)d_in[1];
    const int*   batch= (const int*)d_in[2];
    const float* W1   = (const float*)d_in[3];
    const float* b1   = (const float*)d_in[4];
    const float* W2   = (const float*)d_in[5];
    const float* b2   = (const float*)d_in[6];
    const float* Wl1  = (const float*)d_in[7];
    const float* bl1  = (const float*)d_in[8];
    const float* Wl2  = (const float*)d_in[9];
    const float* bl2  = (const float*)d_in[10];

    const int N = in_sizes[0];
    const int E = in_sizes[1] / 2;
    const int G = out_size / 4;
    const int* srcp = ei;
    const int* dstp = ei + E;
    const int NBUCK = (N + BN - 1) >> BSH;      // 391
    const int NCH   = (E + CHUNK - 1) / CHUNK;  // 196
    const int CAP2  = NCH * SLOT;               // 12544 slots per bucket

    // Workspace: everything fully written before read each run.
    // NO memset, NO global atomics anywhere.
    char* p = (char*)d_ws;
    size_t off = 0;
    int*    cnts  = (int*)(p + off);    off += align_up((size_t)MAXBUCK * CROW * 4, 256);
    int2*   noffs2= (int2*)(p + off);   off += align_up((size_t)N * 8, 16);
    float*  dinv  = (float*)(p + off);  off += align_up((size_t)N * 4, 16);
    float*  xd    = (float*)(p + off);  off += align_up((size_t)N * 4, 16);
    float2* uv    = (float2*)(p + off); off += align_up((size_t)N * 8, 16);
    int*    gstart= (int*)(p + off);    off += align_up((size_t)(G + 1) * 4, 256);
    int*    ebuf  = (int*)(p + off);    off += align_up((size_t)NBUCK * CAP2 * 4, 256);
    int*    ebuf2 = (int*)(p + off);    off += align_up((size_t)NBUCK * CAP * 4, 256);
    (void)ws_size; (void)n_in;

    const int NB4 = (4 * N + 511) / 512;

    k_sortscatter<<<NCH, 1024, 0, stream>>>(srcp, dstp, cnts, ebuf, E, NBUCK, CAP2);
    k_nsort      <<<NBUCK, 512, 0, stream>>>(ebuf, cnts, x, dinv, xd, noffs2, ebuf2,
                                             N, NCH, CAP2);
    k_t          <<<NB4, 512, 0, stream>>>(ebuf2, noffs2, xd, dinv, batch, gstart, uv, N, G);
    k_tda_pool   <<<G, 512, 0, stream>>>(ebuf2, noffs2, uv, gstart, W1, b1, W2, b2,
                                         Wl1, bl1, Wl2, bl2, (float*)d_out, N);
}

// Round 11
// 126.777 us; speedup vs baseline: 1.0267x; 1.0267x over previous
//
#include <hip/hip_runtime.h>
#include <stdint.h>

// 2-layer GCN + global mean pool + MLP head. N=100000, E=1600000, G=512. fp32.
//
// Fully scalarized: the whole GNN reduces to 3 scalar segment-sums per node
// (deg; tf = sum xd[src]; (T,D,A) = sum (u,v,|u|)[src]) + a rank-3 epilogue:
//   h2[d,j] = relu(a*alpha_j + b*beta_j + c*gamma_j + b2_j), alpha/beta/gamma
//   fold W1/b1 through W2 (exact for any b1). Then mean-pool + MLP head.
//
// Round-29: REVERT to verified r27 (127.7 us, session best) + footprint
// shrink CAP 8192->6144 (max bucket ~4400): ebuf+ebuf2 25.6->19.2 MB ->
// less line traffic + better per-XCD L2 residency for CSR re-reads.
// r28 lesson (REGRESSED +2.5us): static sparse slotting's 3x line traffic
// costs more than the memset dispatch + reservation atomics it removed ->
// dense coalesced streams win.
// Ledger: dur = 41 us harness re-poison fill (fixed, 256 MB workspace)
// + ~87 us pipeline (4 stream-ordered phases = dependency minimum).
// Banned forever: per-edge global atomics (r10/r13); agent-scope spin
// grid-barriers (r21); cooperative-launch API (r19). Known-bad: split
// LDS-bin back-end (r20); wave-private cursors (r23); sparse static
// slotting (r28).

#define CHUNK   8192
#define MAXBUCK 400     // NBUCK = ceil(100000/256) = 391
#define BSH     8
#define BN      256
#define CAP     6144    // slots per bucket region (max fill ~4400)
#define CPAD    16      // cursor padding: one per 64 B line
#define ECAP3   6912    // nsort sorted LDS: CAP + 3*256 pad

static inline size_t align_up(size_t x, size_t a){ return (x + a - 1) & ~(a - 1); }

// --- hist(+rank) + early global reservation + scan + sorted LDS + flush ---
__global__ void __launch_bounds__(1024) k_sortscatter(
        const int* __restrict__ src, const int* __restrict__ dst,
        int* __restrict__ gcur, int* __restrict__ ebuf, int E, int nbuck){
    __shared__ int    h[MAXBUCK];       // hist -> local sorted start
    __shared__ int    gofull[MAXBUCK];  // b*CAP + run[b] - localstart[b]
    __shared__ int    lds_e[CHUNK];     // sorted packed edges
    __shared__ unsigned short lds_b[CHUNK]; // bucket id per sorted slot
    __shared__ int    wsum[16];
    int t = threadIdx.x;
    if (t < MAXBUCK) h[t] = 0;
    __syncthreads();
    int base = blockIdx.x * CHUNK;
    int end = min(base + CHUNK, E);
    int ntot = end - base;
    int i = base + t * 8;
    bool vec = (i + 7 < end);
    int4 sa0, sa1, da0, da1;
    int r0=0,r1=0,r2=0,r3=0,r4=0,r5=0,r6=0,r7=0;
    if (vec){
        sa0 = *(const int4*)(src + i);
        sa1 = *(const int4*)(src + i + 4);
        da0 = *(const int4*)(dst + i);
        da1 = *(const int4*)(dst + i + 4);
        r0 = atomicAdd(&h[da0.x >> BSH], 1);   // rank captured in hist pass
        r1 = atomicAdd(&h[da0.y >> BSH], 1);
        r2 = atomicAdd(&h[da0.z >> BSH], 1);
        r3 = atomicAdd(&h[da0.w >> BSH], 1);
        r4 = atomicAdd(&h[da1.x >> BSH], 1);
        r5 = atomicAdd(&h[da1.y >> BSH], 1);
        r6 = atomicAdd(&h[da1.z >> BSH], 1);
        r7 = atomicAdd(&h[da1.w >> BSH], 1);
    }
    int vend = base + (ntot & ~7);
    int srem = 0, drem = 0, rrem = 0;
    bool hasrem = false;
    for (int j = vend + t; j < end; j += 1024){   // <=7 edges total
        srem = src[j]; drem = dst[j];
        rrem = atomicAdd(&h[drem >> BSH], 1);
        hasrem = true;
    }
    __syncthreads();
    // EARLY global reservation: issue before the scan so the cross-XCD
    // atomic round-trip hides under the scan's ~500 cycles.
    int v = (t < nbuck) ? h[t] : 0;
    int run = 0;
    if (t < nbuck && v > 0) run = atomicAdd(&gcur[t * CPAD], v);
    // exclusive scan over v (independent of 'run')
    int lane = t & 63, wv = t >> 6;
    int sc = v;
    #pragma unroll
    for (int off = 1; off < 64; off <<= 1){
        int o = __shfl_up(sc, off);
        if (lane >= off) sc += o;
    }
    if (lane == 63) wsum[wv] = sc;
    __syncthreads();
    if (t < nbuck){
        int wo = 0;
        #pragma unroll
        for (int k = 0; k < 16; ++k) if (k < wv) wo += wsum[k];
        int excl = sc - v + wo;          // local sorted start of bucket t
        h[t] = excl;
        gofull[t] = t * CAP + run - excl;   // waits on atomic result HERE
    }
    __syncthreads();
    // sorted LDS build from register-held ranks (no second atomic pass)
    if (vec){
        int b0 = da0.x >> BSH, b1 = da0.y >> BSH, b2 = da0.z >> BSH, b3 = da0.w >> BSH;
        int b4 = da1.x >> BSH, b5 = da1.y >> BSH, b6 = da1.z >> BSH, b7 = da1.w >> BSH;
        int p0 = h[b0] + r0, p1 = h[b1] + r1, p2 = h[b2] + r2, p3 = h[b3] + r3;
        int p4 = h[b4] + r4, p5 = h[b5] + r5, p6 = h[b6] + r6, p7 = h[b7] + r7;
        lds_e[p0] = (sa0.x << BSH) | (da0.x & (BN - 1));  lds_b[p0] = (unsigned short)b0;
        lds_e[p1] = (sa0.y << BSH) | (da0.y & (BN - 1));  lds_b[p1] = (unsigned short)b1;
        lds_e[p2] = (sa0.z << BSH) | (da0.z & (BN - 1));  lds_b[p2] = (unsigned short)b2;
        lds_e[p3] = (sa0.w << BSH) | (da0.w & (BN - 1));  lds_b[p3] = (unsigned short)b3;
        lds_e[p4] = (sa1.x << BSH) | (da1.x & (BN - 1));  lds_b[p4] = (unsigned short)b4;
        lds_e[p5] = (sa1.y << BSH) | (da1.y & (BN - 1));  lds_b[p5] = (unsigned short)b5;
        lds_e[p6] = (sa1.z << BSH) | (da1.z & (BN - 1));  lds_b[p6] = (unsigned short)b6;
        lds_e[p7] = (sa1.w << BSH) | (da1.w & (BN - 1));  lds_b[p7] = (unsigned short)b7;
    }
    if (hasrem){
        int b = drem >> BSH;
        int p = h[b] + rrem;
        lds_e[p] = (srem << BSH) | (drem & (BN - 1));
        lds_b[p] = (unsigned short)b;
    }
    __syncthreads();
    // coalesced flush: consecutive lanes -> consecutive sorted slots
    for (int j = t; j < ntot; j += 1024){
        int b = lds_b[j];
        ebuf[gofull[b] + j] = lds_e[j];
    }
}

// --- node-level sort within bucket: one-pass rank capture (edges+ranks in
//     registers), node-sorted LDS build, coalesced flush. degree/dinv/xd
//     fall out free. Per-node CSR segment starts padded to %4. ---
__global__ void __launch_bounds__(512) k_nsort(
        const int* __restrict__ ebuf, const int* __restrict__ gcur,
        const float* __restrict__ x, float* __restrict__ dinv,
        float* __restrict__ xd, int2* __restrict__ noffs2,
        int* __restrict__ ebuf2, int N){
    __shared__ int sorted_[ECAP3];
    __shared__ int cnt[BN];
    __shared__ int wsum[4];
    __shared__ int sptot;
    int b = blockIdx.x, node0 = b << BSH, t = threadIdx.x;
    int beg = b * CAP;
    int ecnt = gcur[b * CPAD];
    if (t < BN) cnt[t] = 0;
    __syncthreads();
    int e4 = ecnt & ~3;
    int4 qv[4], rv[4];
    #pragma unroll
    for (int k = 0; k < 4; ++k){
        int i = t * 4 + k * 2048;
        if (i < e4){
            qv[k] = *(const int4*)(ebuf + beg + i);
            rv[k].x = atomicAdd(&cnt[qv[k].x & (BN - 1)], 1);
            rv[k].y = atomicAdd(&cnt[qv[k].y & (BN - 1)], 1);
            rv[k].z = atomicAdd(&cnt[qv[k].z & (BN - 1)], 1);
            rv[k].w = atomicAdd(&cnt[qv[k].w & (BN - 1)], 1);
        }
    }
    int erem = 0, rrem = 0;
    bool hasrem = false;
    for (int j = e4 + t; j < ecnt; j += 512){     // <=3 edges total
        erem = ebuf[beg + j];
        rrem = atomicAdd(&cnt[erem & (BN - 1)], 1);
        hasrem = true;
    }
    __syncthreads();
    int lane = t & 63, wv = t >> 6;
    int myc = 0, v = 0, sc = 0;
    if (t < BN){
        myc = cnt[t];
        v = (myc + 3) & ~3;               // padded count -> aligned starts
        sc = v;
        #pragma unroll
        for (int off = 1; off < 64; off <<= 1){
            int o = __shfl_up(sc, off);   // waves 0..3 fully active
            if (lane >= off) sc += o;
        }
        if (lane == 63) wsum[wv] = sc;
    }
    __syncthreads();
    if (t < BN){
        int wo = 0;
        #pragma unroll
        for (int k = 0; k < 4; ++k) if (k < wv) wo += wsum[k];
        int excl = sc - v + wo;           // exclusive padded prefix (local)
        cnt[t] = excl;
        int n = node0 + t;
        if (n < N){
            noffs2[n] = make_int2(beg + excl, myc);
            float di = rsqrtf((float)myc + 1.0f);
            dinv[n] = di;
            xd[n] = x[n] * di;
        }
    }
    if (t == 0) sptot = 0;
    __syncthreads();
    if (t == 0) sptot = wsum[0] + wsum[1] + wsum[2] + wsum[3];
    // node-sorted LDS build from register-held ranks
    #pragma unroll
    for (int k = 0; k < 4; ++k){
        int i = t * 4 + k * 2048;
        if (i < e4){
            sorted_[cnt[qv[k].x & (BN - 1)] + rv[k].x] = qv[k].x >> BSH;
            sorted_[cnt[qv[k].y & (BN - 1)] + rv[k].y] = qv[k].y >> BSH;
            sorted_[cnt[qv[k].z & (BN - 1)] + rv[k].z] = qv[k].z >> BSH;
            sorted_[cnt[qv[k].w & (BN - 1)] + rv[k].w] = qv[k].w >> BSH;
        }
    }
    if (hasrem)
        sorted_[cnt[erem & (BN - 1)] + rrem] = erem >> BSH;
    __syncthreads();
    // coalesced flush (pad slots carry garbage; never read downstream)
    int ptot = sptot;
    for (int j = t; j < ptot; j += 512)
        ebuf2[beg + j] = sorted_[j];
}

// --- tf[n] = sum xd[src]; 4 threads per node, shfl combine.
//     Also emits gstart[0..G] from batch transitions. ---
__global__ void __launch_bounds__(512) k_t(
        const int* __restrict__ ebuf2, const int2* __restrict__ noffs2,
        const float* __restrict__ xd, const float* __restrict__ dinv,
        const int* __restrict__ batch, int* __restrict__ gstart,
        float2* __restrict__ uv, int N, int G){
    int idx = blockIdx.x * 512 + threadIdx.x;
    int n = idx >> 2, q = idx & 3;
    float s = 0.f;
    int2 o = make_int2(0, 0);
    if (n < N){
        o = noffs2[n];
        int vEnd = o.x + (o.y & ~3);
        for (int i = o.x + q * 4; i < vEnd; i += 16){
            int4 e = *(const int4*)(ebuf2 + i);
            s += xd[e.x] + xd[e.y] + xd[e.z] + xd[e.w];
        }
        if (q == 0)
            for (int i = vEnd; i < o.x + o.y; ++i) s += xd[ebuf2[i]];
    }
    s += __shfl_xor(s, 1);
    s += __shfl_xor(s, 2);
    if (n < N && q == 0){
        float di = dinv[n];
        uv[n] = make_float2(di * di * (s + xd[n]), di);
        // graph boundary emission: every g in [0,G] written exactly once
        int b0 = batch[n];
        int bp = (n == 0) ? -1 : batch[n - 1];
        for (int g = bp + 1; g <= b0; ++g) gstart[g] = n;
        if (n == N - 1)
            for (int g = b0 + 1; g <= G; ++g) gstart[g] = N;
    }
}

// --- fused: per-node (T,D,A) (pair-per-node) + abg fold + pool + head ---
__global__ void __launch_bounds__(512) k_tda_pool(
        const int* __restrict__ ebuf2, const int2* __restrict__ noffs2,
        const float2* __restrict__ uv, const int* __restrict__ gstart,
        const float* __restrict__ W1, const float* __restrict__ b1,
        const float* __restrict__ W2, const float* __restrict__ b2,
        const float* __restrict__ Wl1, const float* __restrict__ bl1,
        const float* __restrict__ Wl2, const float* __restrict__ bl2,
        float* __restrict__ out, int N){
    __shared__ float sa[256], sb[256], sc[256];
    __shared__ float psum[512];
    __shared__ float pooled[128];
    __shared__ float h3s[64];
    int g = blockIdx.x;
    int t = threadIdx.x;           // 512
    int col = t & 127, sub = t >> 7;   // 4 subs of 128 cols
    float al = 0.f, be = 0.f, ga = 0.f;
    #pragma unroll
    for (int c = 0; c < 64; ++c){
        float w2 = W2[c * 128 + col];
        al = fmaf(W1[c], w2, al);
        be = fmaf(b1[c], w2, be);
        ga = fmaf(fabsf(W1[c]), w2, ga);
    }
    float b2j = b2[col];
    int lo = gstart[g], lo2 = gstart[g + 1];
    int cnt = lo2 - lo;
    float pool = 0.f;
    int k = t >> 1, half = t & 1;
    for (int base = lo; base < lo2; base += 256){
        int nn = min(256, lo2 - base);
        float T = 0.f, D = 0.f, A = 0.f;
        if (k < nn){
            int n = base + k;
            int2 o = noffs2[n];
            int vEnd = o.x + (o.y & ~3);
            for (int i = o.x + half * 4; i < vEnd; i += 8){
                int4 q = *(const int4*)(ebuf2 + i);
                float2 w0 = uv[q.x], w1 = uv[q.y], w2v = uv[q.z], w3 = uv[q.w];
                T += w0.x + w1.x + w2v.x + w3.x;
                D += w0.y + w1.y + w2v.y + w3.y;
                A += fabsf(w0.x) + fabsf(w1.x) + fabsf(w2v.x) + fabsf(w3.x);
            }
            if (half == 0)
                for (int i = vEnd; i < o.x + o.y; ++i){
                    float2 wv = uv[ebuf2[i]];
                    T += wv.x; D += wv.y; A += fabsf(wv.x);
                }
        }
        T += __shfl_xor(T, 1);
        D += __shfl_xor(D, 1);
        A += __shfl_xor(A, 1);
        if (k < nn && half == 0){
            float2 wv = uv[base + k];
            float hv = 0.5f * wv.y;
            sa[k] = hv * (T + wv.x);
            sb[k] = hv * (D + wv.y);
            sc[k] = hv * (A + fabsf(wv.x));
        }
        __syncthreads();
        for (int u = sub; u < nn; u += 4){
            float h = fmaf(sa[u], al, fmaf(sb[u], be, fmaf(sc[u], ga, b2j)));
            pool += fmaxf(h, 0.f);
        }
        __syncthreads();
    }
    psum[t] = pool;
    __syncthreads();
    if (t < 128)
        pooled[t] = (psum[t] + psum[t + 128] + psum[t + 256] + psum[t + 384])
                    / (float)(cnt > 0 ? cnt : 1);
    __syncthreads();
    if (t < 64){
        float a = bl1[t];
        #pragma unroll
        for (int kk = 0; kk < 128; ++kk) a = fmaf(pooled[kk], Wl1[kk * 64 + t], a);
        h3s[t] = fmaxf(a, 0.f);
    }
    __syncthreads();
    if (t < 4){
        float o = bl2[t];
        #pragma unroll
        for (int j = 0; j < 64; ++j) o = fmaf(h3s[j], Wl2[j * 4 + t], o);
        out[g * 4 + t] = o;
    }
}

extern "C" void kernel_launch(void* const* d_in, const int* in_sizes, int n_in,
                              void* d_out, int out_size, void* d_ws, size_t ws_size,
                              hipStream_t stream) {
    const float* x    = (const float*)d_in[0];
    const int*   ei   = (const int*)d_in[1];
    const int*   batch= (const int*)d_in[2];
    const float* W1   = (const float*)d_in[3];
    const float* b1   = (const float*)d_in[4];
    const float* W2   = (const float*)d_in[5];
    const float* b2   = (const float*)d_in[6];
    const float* Wl1  = (const float*)d_in[7];
    const float* bl1  = (const float*)d_in[8];
    const float* Wl2  = (const float*)d_in[9];
    const float* bl2  = (const float*)d_in[10];

    const int N = in_sizes[0];
    const int E = in_sizes[1] / 2;
    const int G = out_size / 4;
    const int* srcp = ei;
    const int* dstp = ei + E;
    const int NBUCK = (N + BN - 1) >> BSH;      // 391
    const int NCH   = (E + CHUNK - 1) / CHUNK;  // 196

    // Workspace: gcur (must start 0 -> tiny memset), rest fully written
    // before read. No per-edge global atomics anywhere.
    char* p = (char*)d_ws;
    size_t off = 0;
    int*    gcur  = (int*)(p + off);    off += align_up((size_t)MAXBUCK * CPAD * 4, 256);
    size_t zero_bytes = off;
    int2*   noffs2= (int2*)(p + off);   off += align_up((size_t)N * 8, 16);
    float*  dinv  = (float*)(p + off);  off += align_up((size_t)N * 4, 16);
    float*  xd    = (float*)(p + off);  off += align_up((size_t)N * 4, 16);
    float2* uv    = (float2*)(p + off); off += align_up((size_t)N * 8, 16);
    int*    gstart= (int*)(p + off);    off += align_up((size_t)(G + 1) * 4, 256);
    int*    ebuf  = (int*)(p + off);    off += align_up((size_t)NBUCK * CAP * 4, 256);
    int*    ebuf2 = (int*)(p + off);    off += align_up((size_t)NBUCK * CAP * 4, 256);
    (void)ws_size; (void)n_in;

    hipMemsetAsync(gcur, 0, zero_bytes, stream);

    const int NB4 = (4 * N + 511) / 512;

    k_sortscatter<<<NCH, 1024, 0, stream>>>(srcp, dstp, gcur, ebuf, E, NBUCK);
    k_nsort      <<<NBUCK, 512, 0, stream>>>(ebuf, gcur, x, dinv, xd, noffs2, ebuf2, N);
    k_t          <<<NB4, 512, 0, stream>>>(ebuf2, noffs2, xd, dinv, batch, gstart, uv, N, G);
    k_tda_pool   <<<G, 512, 0, stream>>>(ebuf2, noffs2, uv, gstart, W1, b1, W2, b2,
                                         Wl1, bl1, Wl2, bl2, (float*)d_out, N);
}